// Round 1
// baseline (1414.767 us; speedup 1.0000x reference)
//
#include <hip/hip_runtime.h>
#include <hip/hip_bf16.h>

// Problem constants (from reference)
constexpr int B_   = 32;
constexpr int CIN  = 64;
constexpr int HIN  = 128;
constexpr int WIN  = 128;
constexpr int COUT = 128;
constexpr int HO   = 126;   // 128 - 3 + 1
constexpr int WO   = 126;
constexpr int HP   = 63;    // after 2x2 maxpool
constexpr int WP   = 63;
constexpr int NG   = 8;
constexpr int CG   = COUT / NG;  // 16 channels per group
constexpr float EPS = 1e-5f;

// Tiling for conv kernel
constexpr int TILE = 16;   // 16x16 output pixels per block
constexpr int COT  = 64;   // couts per block (grid.y = 2)
constexpr int CCH  = 4;    // cin chunk staged in LDS

// ws layout: [0 .. 2KB) float stats (B*NG*2 = 512 floats), y (bf16) at +4096 bytes

__global__ __launch_bounds__(256, 2)
void conv_stats_kernel(const float* __restrict__ x, const float* __restrict__ Wg,
                       const float* __restrict__ bias,
                       __hip_bfloat16* __restrict__ y, float* __restrict__ stats)
{
    const int tid  = threadIdx.x;
    const int tpx  = tid & 15;   // output row within tile (this thread owns the whole 16-wide row)
    const int tco  = tid >> 4;   // 0..15 -> group of 4 consecutive couts
    const int tilex = blockIdx.x & 7;
    const int tiley = blockIdx.x >> 3;
    const int co0  = blockIdx.y * COT;
    const int b    = blockIdx.z;
    const int ho0  = tiley * TILE;
    const int wo0  = tilex * TILE;

    __shared__ float sx[CCH][TILE + 2][TILE + 2];  // 4*18*18*4 = 5.1 KB
    __shared__ float sw[CCH][9][COT];              // 4*9*64*4  = 9.2 KB
    __shared__ float sred[4][2];                   // 4 groups per block x (sum, sumsq)

    float acc[4][16];
    #pragma unroll
    for (int j = 0; j < 4; ++j)
        #pragma unroll
        for (int p = 0; p < 16; ++p) acc[j][p] = 0.0f;

    if (tid < 8) sred[tid >> 1][tid & 1] = 0.0f;

    for (int ch = 0; ch < CIN / CCH; ++ch) {
        const int cin0 = ch * CCH;
        __syncthreads();  // protect LDS from previous iteration's readers (also covers sred zeroing)
        // stage x tile (with halo), zero-pad out-of-range (only feeds masked-out outputs)
        for (int i = tid; i < CCH * 18 * 18; i += 256) {
            const int c   = i / 324;
            const int rem = i % 324;
            const int r   = rem / 18;
            const int cc  = rem % 18;
            const int gh  = ho0 + r;
            const int gw  = wo0 + cc;
            float v = 0.0f;
            if (gh < HIN && gw < WIN)
                v = x[(((size_t)b * CIN + cin0 + c) * HIN + gh) * WIN + gw];
            sx[c][r][cc] = v;
        }
        // stage W chunk, transposed to [cin][k][cout] for vector reads
        for (int i = tid; i < CCH * 9 * COT; i += 256) {
            const int c   = i / (9 * COT);
            const int rem = i % (9 * COT);
            const int kk  = rem / COT;
            const int co  = rem % COT;
            sw[c][kk][co] = Wg[((size_t)(co0 + co) * CIN + cin0 + c) * 9 + kk];
        }
        __syncthreads();

        #pragma unroll
        for (int c = 0; c < CCH; ++c) {
            #pragma unroll
            for (int kh = 0; kh < 3; ++kh) {
                float xr[18];
                #pragma unroll
                for (int i = 0; i < 18; ++i) xr[i] = sx[c][tpx + kh][i];
                #pragma unroll
                for (int kw = 0; kw < 3; ++kw) {
                    const float4 wv = *(const float4*)(&sw[c][kh * 3 + kw][tco << 2]);
                    #pragma unroll
                    for (int p = 0; p < 16; ++p) {
                        const float xv = xr[p + kw];
                        acc[0][p] = fmaf(wv.x, xv, acc[0][p]);
                        acc[1][p] = fmaf(wv.y, xv, acc[1][p]);
                        acc[2][p] = fmaf(wv.z, xv, acc[2][p]);
                        acc[3][p] = fmaf(wv.w, xv, acc[3][p]);
                    }
                }
            }
        }
    }

    // epilogue: bias add, bf16 store, partial group stats
    const int ho = ho0 + tpx;
    const bool rowok = (ho < HO);
    float s1 = 0.0f, s2 = 0.0f;

    #pragma unroll
    for (int j = 0; j < 4; ++j) {
        const int co = co0 + (tco << 2) + j;
        const float bv = bias[co];
        float v[16];
        #pragma unroll
        for (int p = 0; p < 16; ++p) v[p] = acc[j][p] + bv;
        if (rowok) {
            #pragma unroll
            for (int p = 0; p < 16; ++p) {
                if (wo0 + p < WO) { s1 += v[p]; s2 += v[p] * v[p]; }
            }
            const size_t rowbase = (((size_t)b * COUT + co) * HO + ho) * WO;
            #pragma unroll
            for (int pp = 0; pp < 8; ++pp) {
                const int wo = wo0 + 2 * pp;
                if (wo < WO) {
                    __hip_bfloat162 pr;
                    pr.x = __float2bfloat16(v[2 * pp]);
                    pr.y = __float2bfloat16(v[2 * pp + 1]);
                    *(__hip_bfloat162*)(y + rowbase + wo) = pr;
                }
            }
        }
    }

    // block-level group reduction (4 consecutive couts of one thread are always in one group)
    __syncthreads();  // ensure sred zeroing visible & no LDS hazards
    const int gl = tco >> 2;  // local group 0..3
    atomicAdd(&sred[gl][0], s1);
    atomicAdd(&sred[gl][1], s2);
    __syncthreads();
    if (tid < 8) {
        const int g = (co0 >> 4) + (tid >> 1);
        atomicAdd(&stats[((size_t)b * NG + g) * 2 + (tid & 1)], sred[tid >> 1][tid & 1]);
    }
}

__global__ __launch_bounds__(256)
void gn_pool_kernel(const __hip_bfloat16* __restrict__ y, const float* __restrict__ stats,
                    const float* __restrict__ gamma, const float* __restrict__ beta,
                    const float* __restrict__ scale, float* __restrict__ out)
{
    const int idx = blockIdx.x * 256 + threadIdx.x;
    if (idx >= B_ * COUT * HP * WP) return;
    const int w = idx % WP;
    const int h = (idx / WP) % HP;
    const int c = (idx / (WP * HP)) % COUT;
    const int b = idx / (WP * HP * COUT);
    const int g = c >> 4;

    const float s1 = stats[((size_t)b * NG + g) * 2 + 0];
    const float s2 = stats[((size_t)b * NG + g) * 2 + 1];
    constexpr float inv = 1.0f / (float)(CG * HO * WO);
    const float mean = s1 * inv;
    const float var  = fmaf(-mean, mean, s2 * inv);
    const float rstd = rsqrtf(var + EPS);
    const float sc   = scale[c];
    const float a    = rstd * gamma[c] * sc;
    const float bb   = fmaf(-mean, a, beta[c] * sc);  // (beta - mean*rstd*gamma)*scale

    const size_t base = (((size_t)b * COUT + c) * HO + 2 * h) * WO + 2 * w;
    const __hip_bfloat162 r0 = *(const __hip_bfloat162*)(y + base);
    const __hip_bfloat162 r1 = *(const __hip_bfloat162*)(y + base + WO);
    const float v00 = fmaf(__bfloat162float(r0.x), a, bb);
    const float v01 = fmaf(__bfloat162float(r0.y), a, bb);
    const float v10 = fmaf(__bfloat162float(r1.x), a, bb);
    const float v11 = fmaf(__bfloat162float(r1.y), a, bb);
    float m = fmaxf(fmaxf(v00, v01), fmaxf(v10, v11));
    m = fminf(fmaxf(m, 0.0f), 1.0f);
    out[idx] = m;
}

extern "C" void kernel_launch(void* const* d_in, const int* in_sizes, int n_in,
                              void* d_out, int out_size, void* d_ws, size_t ws_size,
                              hipStream_t stream)
{
    const float* x     = (const float*)d_in[0];
    const float* W     = (const float*)d_in[1];
    const float* bias  = (const float*)d_in[2];
    const float* scale = (const float*)d_in[3];
    const float* gamma = (const float*)d_in[4];
    const float* beta  = (const float*)d_in[5];

    float* stats = (float*)d_ws;
    __hip_bfloat16* y = (__hip_bfloat16*)((char*)d_ws + 4096);
    float* out = (float*)d_out;

    hipMemsetAsync(stats, 0, B_ * NG * 2 * sizeof(float), stream);

    conv_stats_kernel<<<dim3(64, 2, 32), 256, 0, stream>>>(x, W, bias, y, stats);

    const int total = B_ * COUT * HP * WP;  // 16,257,024 -> exactly 63504 blocks
    gn_pool_kernel<<<(total + 255) / 256, 256, 0, stream>>>(y, stats, gamma, beta, scale, out);
}

// Round 2
// 509.752 us; speedup vs baseline: 2.7754x; 2.7754x over previous
//
#include <hip/hip_runtime.h>
#include <hip/hip_bf16.h>

// Problem constants
constexpr int B_   = 32;
constexpr int CIN  = 64;
constexpr int HIN  = 128;
constexpr int WIN  = 128;
constexpr int COUT = 128;
constexpr int HO   = 126;
constexpr int WO   = 126;
constexpr int HP   = 63;
constexpr int WP   = 63;
constexpr int NG   = 8;
constexpr float EPS = 1e-5f;

typedef _Float16 f16x8 __attribute__((ext_vector_type(8)));
typedef _Float16 f16x4 __attribute__((ext_vector_type(4)));
typedef _Float16 f16x2 __attribute__((ext_vector_type(2)));
typedef float    f32x4 __attribute__((ext_vector_type(4)));

// ws layout: stats @0 (4KB) | Wh @4096 (147456 B) | y @163840 (f16, 130 MB)

// ---------- Prep: W (OIHW fp32) -> Wh[kh*kw][cout][cin] f16 ----------
__global__ __launch_bounds__(256)
void whprep_kernel(const float* __restrict__ W, _Float16* __restrict__ Wh)
{
    int i = blockIdx.x * 256 + threadIdx.x;
    if (i >= 9 * COUT * CIN) return;
    int c  = i & 63;
    int co = (i >> 6) & 127;
    int kk = i >> 13;               // 128*64 = 8192
    Wh[i] = (_Float16)W[((size_t)co * CIN + c) * 9 + kk];
}

// ---------- Conv (implicit GEMM, MFMA f16) + bias + stats ----------
// block: 128 threads = 2 waves. Each wave: M=128 pixels (one output row) x N=32 couts.
// grid: (126 rows, 32 batch, 2 cout-halves)
__global__ __launch_bounds__(128, 2)
void conv_mfma_kernel(const float* __restrict__ x, const _Float16* __restrict__ Wh,
                      const float* __restrict__ bias,
                      _Float16* __restrict__ y, float* __restrict__ stats)
{
    const int tid   = threadIdx.x;
    const int lane  = tid & 63;
    const int wave  = tid >> 6;          // 0..1
    const int ln    = lane & 15;         // n-lane (cout within 16-tile) / m-lane for A
    const int jq    = lane >> 4;         // 0..3 quad
    const int ho    = blockIdx.x;        // output row, input rows ho..ho+2
    const int b     = blockIdx.y;
    const int cobase = blockIdx.z * 64 + wave * 32;

    // LDS x-tile: [3 rows][130 cols][32 cin + 8 pad] f16 (col stride 80 B)
    __shared__ _Float16 sx[3][130][40];

    f32x4 acc[8][2];
    #pragma unroll
    for (int mt = 0; mt < 8; ++mt)
        #pragma unroll
        for (int nt = 0; nt < 2; ++nt)
            acc[mt][nt] = (f32x4){0.f, 0.f, 0.f, 0.f};

    for (int chunk = 0; chunk < 2; ++chunk) {
        __syncthreads();   // previous chunk's readers done before overwrite
        // ---- stage x chunk: 32 cin x 3 rows x 128 cols, fp32 -> f16 ----
        // unit u: cq = u&7 (cin quad), pr = (u>>3)&63 (col pair), r = u>>9 (row)
        #pragma unroll
        for (int s = 0; s < 12; ++s) {
            const int u  = s * 128 + tid;
            const int cq = u & 7;
            const int pr = (u >> 3) & 63;
            const int r  = u >> 9;
            const float* src = x + ((size_t)(b * CIN + chunk * 32 + cq * 4) * HIN + (ho + r)) * WIN + 2 * pr;
            const float2 v0 = *(const float2*)(src);
            const float2 v1 = *(const float2*)(src + 16384);
            const float2 v2 = *(const float2*)(src + 32768);
            const float2 v3 = *(const float2*)(src + 49152);
            f16x4 w0 = {(_Float16)v0.x, (_Float16)v1.x, (_Float16)v2.x, (_Float16)v3.x};
            f16x4 w1 = {(_Float16)v0.y, (_Float16)v1.y, (_Float16)v2.y, (_Float16)v3.y};
            *(f16x4*)(&sx[r][2 * pr][cq * 4])     = w0;
            *(f16x4*)(&sx[r][2 * pr + 1][cq * 4]) = w1;
        }
        // ---- load B fragments for this chunk (global, L2-hot) ----
        f16x8 Bf[2][9];
        #pragma unroll
        for (int kk = 0; kk < 9; ++kk)
            #pragma unroll
            for (int nt = 0; nt < 2; ++nt)
                Bf[nt][kk] = *(const f16x8*)(Wh + ((size_t)(kk * COUT + cobase + nt * 16 + ln) * CIN
                                                  + chunk * 32 + jq * 8));
        __syncthreads();
        // ---- MFMA main loop: 9 shifts x 8 mtiles x 2 ntiles ----
        #pragma unroll
        for (int kk = 0; kk < 9; ++kk) {
            const int kh = kk / 3, kw = kk % 3;
            #pragma unroll
            for (int mt = 0; mt < 8; ++mt) {
                const f16x8 a = *(const f16x8*)(&sx[kh][mt * 16 + ln + kw][jq * 8]);
                acc[mt][0] = __builtin_amdgcn_mfma_f32_16x16x32_f16(a, Bf[0][kk], acc[mt][0], 0, 0, 0);
                acc[mt][1] = __builtin_amdgcn_mfma_f32_16x16x32_f16(a, Bf[1][kk], acc[mt][1], 0, 0, 0);
            }
        }
    }

    // ---- epilogue: bias, f16 store, group stats ----
    float s1[2] = {0.f, 0.f}, s2[2] = {0.f, 0.f};
    #pragma unroll
    for (int nt = 0; nt < 2; ++nt) {
        const int co = cobase + nt * 16 + ln;
        const float bv = bias[co];
        const size_t plane = ((size_t)(b * COUT + co) * HO + ho) * WO;
        #pragma unroll
        for (int mt = 0; mt < 8; ++mt) {
            const int wo0 = mt * 16 + jq * 4;
            f32x4 v = acc[mt][nt];
            float e0 = v.x + bv, e1 = v.y + bv, e2 = v.z + bv, e3 = v.w + bv;
            // stats over valid pixels
            s1[nt] += e0 + e1;  s2[nt] += e0 * e0 + e1 * e1;   // wo0+1 <= 125 always
            if (wo0 + 3 < WO) { s1[nt] += e2 + e3; s2[nt] += e2 * e2 + e3 * e3; }
            // stores (4-byte f16x2, always 4-aligned)
            *(f16x2*)(y + plane + wo0) = (f16x2){(_Float16)e0, (_Float16)e1};
            if (wo0 + 3 < WO)
                *(f16x2*)(y + plane + wo0 + 2) = (f16x2){(_Float16)e2, (_Float16)e3};
        }
        // wave reduction (all 64 lanes belong to one group for this nt)
        float a1 = s1[nt], a2 = s2[nt];
        #pragma unroll
        for (int off = 32; off > 0; off >>= 1) {
            a1 += __shfl_down(a1, off);
            a2 += __shfl_down(a2, off);
        }
        if (lane == 0) {
            const int g = (cobase >> 4) + nt;
            atomicAdd(&stats[((size_t)b * NG + g) * 2 + 0], a1);
            atomicAdd(&stats[((size_t)b * NG + g) * 2 + 1], a2);
        }
    }
}

// ---------- GroupNorm + scale + maxpool + clamp ----------
__global__ __launch_bounds__(256)
void gn_pool_kernel(const _Float16* __restrict__ y, const float* __restrict__ stats,
                    const float* __restrict__ gamma, const float* __restrict__ beta,
                    const float* __restrict__ scale, float* __restrict__ out)
{
    const int idx = blockIdx.x * 256 + threadIdx.x;
    if (idx >= B_ * COUT * HP * WP) return;
    const int w = idx % WP;
    const int h = (idx / WP) % HP;
    const int c = (idx / (WP * HP)) % COUT;
    const int b = idx / (WP * HP * COUT);
    const int g = c >> 4;

    const float s1 = stats[((size_t)b * NG + g) * 2 + 0];
    const float s2 = stats[((size_t)b * NG + g) * 2 + 1];
    constexpr float inv = 1.0f / (float)((COUT / NG) * HO * WO);
    const float mean = s1 * inv;
    const float var  = fmaf(-mean, mean, s2 * inv);
    const float rstd = rsqrtf(var + EPS);
    const float sc   = scale[c];
    const float a    = rstd * gamma[c] * sc;
    const float bb   = fmaf(-mean, a, beta[c] * sc);

    const size_t base = (((size_t)b * COUT + c) * HO + 2 * h) * WO + 2 * w;
    const f16x2 r0 = *(const f16x2*)(y + base);
    const f16x2 r1 = *(const f16x2*)(y + base + WO);
    const float v00 = fmaf((float)r0.x, a, bb);
    const float v01 = fmaf((float)r0.y, a, bb);
    const float v10 = fmaf((float)r1.x, a, bb);
    const float v11 = fmaf((float)r1.y, a, bb);
    float m = fmaxf(fmaxf(v00, v01), fmaxf(v10, v11));
    m = fminf(fmaxf(m, 0.0f), 1.0f);
    out[idx] = m;
}

extern "C" void kernel_launch(void* const* d_in, const int* in_sizes, int n_in,
                              void* d_out, int out_size, void* d_ws, size_t ws_size,
                              hipStream_t stream)
{
    const float* x     = (const float*)d_in[0];
    const float* W     = (const float*)d_in[1];
    const float* bias  = (const float*)d_in[2];
    const float* scale = (const float*)d_in[3];
    const float* gamma = (const float*)d_in[4];
    const float* beta  = (const float*)d_in[5];

    float*      stats = (float*)d_ws;
    _Float16*   Wh    = (_Float16*)((char*)d_ws + 4096);
    _Float16*   y     = (_Float16*)((char*)d_ws + 163840);
    float*      out   = (float*)d_out;

    hipMemsetAsync(stats, 0, B_ * NG * 2 * sizeof(float), stream);

    whprep_kernel<<<(9 * COUT * CIN + 255) / 256, 256, 0, stream>>>(W, Wh);

    conv_mfma_kernel<<<dim3(HO, B_, 2), 128, 0, stream>>>(x, Wh, bias, y, stats);

    const int total = B_ * COUT * HP * WP;
    gn_pool_kernel<<<(total + 255) / 256, 256, 0, stream>>>(y, stats, gamma, beta, scale, out);
}